// Round 11
// baseline (456.938 us; speedup 1.0000x reference)
//
#include <hip/hip_runtime.h>
#include <hip/hip_bf16.h>

// SparseLinear forward as DENSE bf16 MFMA GEMM:  C = A * B^T + bias (4096^3).
// R11 = R10 + wave-group program-order STAGGER: waves with wr=0 compute
// quadrants (mh0,mh1); waves with wr=1 compute (mh1,mh0) within each k-half.
// SIMD s hosts one wave of each group (waves s and s+4), so one wave MFMAs
// while its SIMD-mate reads -> decorrelates the lockstep read/MFMA bursts
// that made the walls SUM across R2-R10. Ledger/swizzle/epilogue unchanged:
// 256x256 tile, BK=64 (two [256][32] k-units), 8 waves (2Mx4N), 2-deep dbuf,
// counted vmcnt(4) at the two required barriers per K-tile, zero-conflict
// granule-XOR swizzle, setprio around MFMA clusters, fused-bias epilogue.

typedef __bf16 bf16x8 __attribute__((ext_vector_type(8)));
typedef float f32x4 __attribute__((ext_vector_type(4)));

constexpr int M = 4096;   // T*B
constexpr int N = 4096;   // C_OUT
constexpr int K = 4096;   // C_IN
constexpr int BM = 256, BN = 256, BK = 64;
constexpr int NT = K / BK;          // 64 K-tiles
// One dbuf = 32768 elems (64 KiB): [A_k0][A_k1][B_k0][B_k1], each [256][32]
constexpr int DBUF = 32768;
constexpr int A_K0 = 0, A_K1 = 8192, B_K0 = 16384, B_K1 = 24576;

__device__ __forceinline__ unsigned short f2bf_rne(float f) {
    unsigned int u = __float_as_uint(f);
    u += 0x7fffu + ((u >> 16) & 1u);   // round-to-nearest-even
    return (unsigned short)(u >> 16);
}

// Fused convert: x -> Abf and w -> Bbf in one launch.
__global__ __launch_bounds__(256) void cvt_both(const float* __restrict__ x,
                                                const float* __restrict__ w,
                                                unsigned short* __restrict__ Abf,
                                                unsigned short* __restrict__ Bbf) {
    const int n8 = (M * K) / 8;
    int idx = blockIdx.x * blockDim.x + threadIdx.x;
    int stride = gridDim.x * blockDim.x;
    for (int i = idx; i < 2 * n8; i += stride) {
        const float* src;
        unsigned short* dst;
        if (i < n8) { long b = (long)i * 8;        src = x + b; dst = Abf + b; }
        else        { long b = (long)(i - n8) * 8; src = w + b; dst = Bbf + b; }
        float4 v0 = *(const float4*)(src);
        float4 v1 = *(const float4*)(src + 4);
        ushort4 r0, r1;
        r0.x = f2bf_rne(v0.x); r0.y = f2bf_rne(v0.y);
        r0.z = f2bf_rne(v0.z); r0.w = f2bf_rne(v0.w);
        r1.x = f2bf_rne(v1.x); r1.y = f2bf_rne(v1.y);
        r1.z = f2bf_rne(v1.z); r1.w = f2bf_rne(v1.w);
        *(ushort4*)(dst) = r0;
        *(ushort4*)(dst + 4) = r1;
    }
}

// Stage one k-half unit ([256 rows][32 k] = 16 KiB, 2 global_load_lds) into
// LDS (linear dest, pre-swizzled global source: cg ^= (row>>1)&3).
__device__ __forceinline__ void stage_unit(const unsigned short* __restrict__ g,
                                           size_t grow0, int kcol0,
                                           unsigned short* unitbase,
                                           int tid, int wave) {
#pragma unroll
    for (int i = 0; i < 2; ++i) {
        const int row = i * 128 + (tid >> 2);
        const int cg  = (tid & 3) ^ ((row >> 1) & 3);
        const unsigned short* src = g + (grow0 + (size_t)row) * (size_t)K
                                      + (size_t)(kcol0 + cg * 8);
        unsigned short* dst = unitbase + i * 4096 + wave * 512;
        __builtin_amdgcn_global_load_lds(
            (const __attribute__((address_space(1))) void*)src,
            (__attribute__((address_space(3))) void*)dst, 16, 0, 0);
    }
}

// One quadrant: 4 A-frags at (pA + MOFS) x the preloaded b[0..3], accumulating
// into acc[ACB..ACB+3][*]. MOFS/ACB are literal constants (rule #20: keeps
// acc indexing compile-time; no scratch).
#define QUAD(MOFS, ACB)                                                        \
    {                                                                          \
        bf16x8 aq[4];                                                          \
        _Pragma("unroll")                                                      \
        for (int m = 0; m < 4; ++m)                                            \
            aq[m] = *(const bf16x8*)(pA + (MOFS) + m * 512);                   \
        __builtin_amdgcn_s_setprio(1);                                         \
        _Pragma("unroll")                                                      \
        for (int m = 0; m < 4; ++m)                                            \
            _Pragma("unroll")                                                  \
            for (int n = 0; n < 4; ++n)                                        \
                acc[(ACB) + m][n] = __builtin_amdgcn_mfma_f32_16x16x32_bf16(   \
                    aq[m], b[n], acc[(ACB) + m][n], 0, 0, 0);                  \
        __builtin_amdgcn_s_setprio(0);                                         \
    }

__global__ __launch_bounds__(512, 2) void gemm_stag(
    const unsigned short* __restrict__ A,   // [M][K] bf16 bits
    const unsigned short* __restrict__ B,   // [N][K] bf16 bits
    const float* __restrict__ bias,         // [N]
    float* __restrict__ C)                  // [M][N] fp32
{
    __shared__ unsigned short lds[2 * DBUF];   // 128 KiB

    // XCD-aware bijective swizzle: 256 wgs, 256 % 8 == 0
    const int wg = blockIdx.x;
    const int s  = ((wg & 7) << 5) | (wg >> 3);
    const int bm = s >> 4, bn = s & 15;
    const size_t brow = (size_t)bm * BM;
    const size_t bcol = (size_t)bn * BN;

    const int tid  = threadIdx.x;
    const int wave = tid >> 6;
    const int lane = tid & 63;
    const int wr = wave >> 2;       // 0..1  (2 M-waves, 128 rows each) = group
    const int wc = wave & 3;        // 0..3  (4 N-waves, 64 cols each)
    const int lr = lane & 15;       // fragment row-in-16
    const int kg = lane >> 4;       // k-group 0..3

    const int a_row0 = wr * 128 + lr;
    const int b_row0 = wc * 64 + lr;
    const int aoff = a_row0 * 32 + ((kg ^ ((a_row0 >> 1) & 3)) << 3);
    const int boff = b_row0 * 32 + ((kg ^ ((b_row0 >> 1) & 3)) << 3);

    f32x4 acc[8][4];
#pragma unroll
    for (int m = 0; m < 8; ++m)
#pragma unroll
        for (int n = 0; n < 4; ++n)
            acc[m][n] = (f32x4){0.f, 0.f, 0.f, 0.f};

    // ---- prologue: stage tile 0's 4 units (8 loads) ----
    stage_unit(A, brow, 0,  lds + A_K0, tid, wave);
    stage_unit(B, bcol, 0,  lds + B_K0, tid, wave);
    stage_unit(A, brow, 32, lds + A_K1, tid, wave);
    stage_unit(B, bcol, 32, lds + B_K1, tid, wave);
    asm volatile("s_waitcnt vmcnt(4)" ::: "memory");   // A_k0, B_k0 landed
    __builtin_amdgcn_s_barrier();

    for (int t = 0; t < NT; ++t) {
        unsigned short* db = lds + (t & 1) * DBUF;        // compute buffer
        unsigned short* pb = lds + ((t & 1) ^ 1) * DBUF;  // prefetch target
        const int ktn = (t + 1) * BK;
        const bool pf = (t + 1) < NT;

        bf16x8 b[4];

        // ================= half 0 (ks = 0) =================
        if (pf) {
            stage_unit(A, brow, ktn, pb + A_K0, tid, wave);
            stage_unit(B, bcol, ktn, pb + B_K0, tid, wave);
        }
        {
            const unsigned short* pA = db + A_K0 + aoff;
            const unsigned short* pB = db + B_K0 + boff;
#pragma unroll
            for (int n = 0; n < 4; ++n) b[n] = *(const bf16x8*)(pB + n * 512);
            if (wr == 0) { QUAD(0, 0)    QUAD(2048, 4) }   // mh0 then mh1
            else         { QUAD(2048, 4) QUAD(0, 0)    }   // mh1 then mh0
        }
        // W_b: A_k1(t), B_k1(t) (oldest 4 loads) must land before half-1 reads.
        if (pf) { asm volatile("s_waitcnt vmcnt(4)" ::: "memory"); }
        else    { asm volatile("s_waitcnt vmcnt(0)" ::: "memory"); }
        __builtin_amdgcn_s_barrier();

        // ================= half 1 (ks = 1) =================
        if (pf) {
            stage_unit(A, brow, ktn + 32, pb + A_K1, tid, wave);
            stage_unit(B, bcol, ktn + 32, pb + B_K1, tid, wave);
        }
        {
            const unsigned short* pA = db + A_K1 + aoff;
            const unsigned short* pB = db + B_K1 + boff;
#pragma unroll
            for (int n = 0; n < 4; ++n) b[n] = *(const bf16x8*)(pB + n * 512);
            if (wr == 0) { QUAD(0, 0)    QUAD(2048, 4) }
            else         { QUAD(2048, 4) QUAD(0, 0)    }
        }
        // W_a: A_k0(t+1), B_k0(t+1) (oldest 4) must land before next tile.
        if (pf) {
            asm volatile("s_waitcnt vmcnt(4)" ::: "memory");
            __builtin_amdgcn_s_barrier();
        }
    }

    // ---- epilogue: C/D layout col=lane&15, row=(lane>>4)*4+j; fused bias ----
#pragma unroll
    for (int n = 0; n < 4; ++n) {
        const size_t col = bcol + wc * 64 + n * 16 + lr;
        const float bs = bias[col];
#pragma unroll
        for (int m = 0; m < 8; ++m) {
            const size_t row0 = brow + (size_t)wr * 128 + m * 16 + kg * 4;
#pragma unroll
            for (int j = 0; j < 4; ++j) {
                C[(row0 + j) * N + col] = acc[m][n][j] + bs;
            }
        }
    }
}

extern "C" void kernel_launch(void* const* d_in, const int* in_sizes, int n_in,
                              void* d_out, int out_size, void* d_ws, size_t ws_size,
                              hipStream_t stream) {
    const float* x    = (const float*)d_in[0];   // [T,B,C_IN] = [M,K]
    const float* w    = (const float*)d_in[1];   // [C_OUT,C_IN] = [N,K]
    const float* bias = (const float*)d_in[2];   // [N]
    float* out = (float*)d_out;                  // [M,N]

    unsigned short* Abf = (unsigned short*)d_ws;           // 32 MiB
    unsigned short* Bbf = Abf + (size_t)M * K;             // 32 MiB

    cvt_both<<<2048, 256, 0, stream>>>(x, w, Abf, Bbf);

    gemm_stag<<<dim3((M / BM) * (N / BN)), 512, 0, stream>>>(Abf, Bbf, bias, out);
}

// Round 12
// 153.269 us; speedup vs baseline: 2.9813x; 2.9813x over previous
//
#include <hip/hip_runtime.h>
#include <hip/hip_bf16.h>

// SparseLinear forward as DENSE bf16 MFMA GEMM:  C = A * B^T + bias (4096^3).
// R12 = consolidation on the measured session best (R10: 151.8us total,
// GEMM 126.2us / 1090 TF). Structure: 256x256 tile, BK=64 (two [256][32]
// k-units), 8 waves (2Mx4N), 2-deep LDS dbuf (128 KiB), 4 fine phases/K-tile,
// counted vmcnt(4) ledger (never 0 mid-loop), zero-conflict granule-XOR
// swizzle (pre-swizzled global source + swizzled ds_read, SQ_LDS_BANK_CONFLICT
// = 0), setprio around MFMA clusters, fused-bias epilogue, XCD-bijective
// block swizzle. Session ledger: 7 structural variants (2/4/8-phase, free-run,
// 32x32 shape, 2-blocks/CU, wave-stagger, row-sparsity compaction) all landed
// >= this; this is the stable plain-HIP optimum for this workload.

typedef __bf16 bf16x8 __attribute__((ext_vector_type(8)));
typedef float f32x4 __attribute__((ext_vector_type(4)));

constexpr int M = 4096;   // T*B
constexpr int N = 4096;   // C_OUT
constexpr int K = 4096;   // C_IN
constexpr int BM = 256, BN = 256, BK = 64;
constexpr int NT = K / BK;          // 64 K-tiles
// One dbuf = 32768 elems (64 KiB): [A_k0][A_k1][B_k0][B_k1], each [256][32]
constexpr int DBUF = 32768;
constexpr int A_K0 = 0, A_K1 = 8192, B_K0 = 16384, B_K1 = 24576;

__device__ __forceinline__ unsigned short f2bf_rne(float f) {
    unsigned int u = __float_as_uint(f);
    u += 0x7fffu + ((u >> 16) & 1u);   // round-to-nearest-even
    return (unsigned short)(u >> 16);
}

// Fused convert: x -> Abf and w -> Bbf in one launch.
__global__ __launch_bounds__(256) void cvt_both(const float* __restrict__ x,
                                                const float* __restrict__ w,
                                                unsigned short* __restrict__ Abf,
                                                unsigned short* __restrict__ Bbf) {
    const int n8 = (M * K) / 8;
    int idx = blockIdx.x * blockDim.x + threadIdx.x;
    int stride = gridDim.x * blockDim.x;
    for (int i = idx; i < 2 * n8; i += stride) {
        const float* src;
        unsigned short* dst;
        if (i < n8) { long b = (long)i * 8;        src = x + b; dst = Abf + b; }
        else        { long b = (long)(i - n8) * 8; src = w + b; dst = Bbf + b; }
        float4 v0 = *(const float4*)(src);
        float4 v1 = *(const float4*)(src + 4);
        ushort4 r0, r1;
        r0.x = f2bf_rne(v0.x); r0.y = f2bf_rne(v0.y);
        r0.z = f2bf_rne(v0.z); r0.w = f2bf_rne(v0.w);
        r1.x = f2bf_rne(v1.x); r1.y = f2bf_rne(v1.y);
        r1.z = f2bf_rne(v1.z); r1.w = f2bf_rne(v1.w);
        *(ushort4*)(dst) = r0;
        *(ushort4*)(dst + 4) = r1;
    }
}

// Stage one k-half unit ([256 rows][32 k] = 16 KiB, 2 global_load_lds) into
// LDS (linear dest, pre-swizzled global source: cg ^= (row>>1)&3).
__device__ __forceinline__ void stage_unit(const unsigned short* __restrict__ g,
                                           size_t grow0, int kcol0,
                                           unsigned short* unitbase,
                                           int tid, int wave) {
#pragma unroll
    for (int i = 0; i < 2; ++i) {
        const int row = i * 128 + (tid >> 2);
        const int cg  = (tid & 3) ^ ((row >> 1) & 3);
        const unsigned short* src = g + (grow0 + (size_t)row) * (size_t)K
                                      + (size_t)(kcol0 + cg * 8);
        unsigned short* dst = unitbase + i * 4096 + wave * 512;
        __builtin_amdgcn_global_load_lds(
            (const __attribute__((address_space(1))) void*)src,
            (__attribute__((address_space(3))) void*)dst, 16, 0, 0);
    }
}

__global__ __launch_bounds__(512, 2) void gemm_bt_bias_np(
    const unsigned short* __restrict__ A,   // [M][K] bf16 bits
    const unsigned short* __restrict__ B,   // [N][K] bf16 bits
    const float* __restrict__ bias,         // [N]
    float* __restrict__ C)                  // [M][N] fp32
{
    __shared__ unsigned short lds[2 * DBUF];   // 128 KiB

    // XCD-aware bijective swizzle: 256 wgs, 256 % 8 == 0
    const int wg = blockIdx.x;
    const int s  = ((wg & 7) << 5) | (wg >> 3);
    const int bm = s >> 4, bn = s & 15;
    const size_t brow = (size_t)bm * BM;
    const size_t bcol = (size_t)bn * BN;

    const int tid  = threadIdx.x;
    const int wave = tid >> 6;
    const int lane = tid & 63;
    const int wr = wave >> 2;       // 0..1  (2 M-waves, 128 rows each)
    const int wc = wave & 3;        // 0..3  (4 N-waves, 64 cols each)
    const int lr = lane & 15;       // fragment row-in-16
    const int kg = lane >> 4;       // k-group 0..3

    const int a_row0 = wr * 128 + lr;
    const int b_row0 = wc * 64 + lr;
    const int aoff = a_row0 * 32 + ((kg ^ ((a_row0 >> 1) & 3)) << 3);
    const int boff = b_row0 * 32 + ((kg ^ ((b_row0 >> 1) & 3)) << 3);

    f32x4 acc[8][4];
#pragma unroll
    for (int m = 0; m < 8; ++m)
#pragma unroll
        for (int n = 0; n < 4; ++n)
            acc[m][n] = (f32x4){0.f, 0.f, 0.f, 0.f};

    // ---- prologue: stage tile 0's 4 units (8 loads) ----
    stage_unit(A, brow, 0,  lds + A_K0, tid, wave);
    stage_unit(B, bcol, 0,  lds + B_K0, tid, wave);
    stage_unit(A, brow, 32, lds + A_K1, tid, wave);
    stage_unit(B, bcol, 32, lds + B_K1, tid, wave);
    asm volatile("s_waitcnt vmcnt(4)" ::: "memory");   // A_k0, B_k0 landed
    __builtin_amdgcn_s_barrier();

    for (int t = 0; t < NT; ++t) {
        unsigned short* db = lds + (t & 1) * DBUF;        // compute buffer
        unsigned short* pb = lds + ((t & 1) ^ 1) * DBUF;  // prefetch target
        const int ktn = (t + 1) * BK;
        const bool pf = (t + 1) < NT;

        const unsigned short* pA0 = db + A_K0 + aoff;
        const unsigned short* pA1 = db + A_K1 + aoff;
        const unsigned short* pB0 = db + B_K0 + boff;
        const unsigned short* pB1 = db + B_K1 + boff;

        bf16x8 a[4], b[4];

        // ===== P1: quadrant (m-half 0, ks 0); stage A_k0(t+1) =====
#pragma unroll
        for (int n = 0; n < 4; ++n) b[n] = *(const bf16x8*)(pB0 + n * 512);
#pragma unroll
        for (int m = 0; m < 4; ++m) a[m] = *(const bf16x8*)(pA0 + m * 512);
        if (pf) stage_unit(A, brow, ktn, pb + A_K0, tid, wave);
        __builtin_amdgcn_s_barrier();
        __builtin_amdgcn_s_setprio(1);
#pragma unroll
        for (int m = 0; m < 4; ++m)
#pragma unroll
            for (int n = 0; n < 4; ++n)
                acc[m][n] = __builtin_amdgcn_mfma_f32_16x16x32_bf16(
                    a[m], b[n], acc[m][n], 0, 0, 0);
        __builtin_amdgcn_s_setprio(0);
        __builtin_amdgcn_s_barrier();

        // ===== P2: quadrant (m-half 1, ks 0), B reused; stage B_k0(t+1) =====
#pragma unroll
        for (int m = 0; m < 4; ++m) a[m] = *(const bf16x8*)(pA0 + 2048 + m * 512);
        if (pf) stage_unit(B, bcol, ktn, pb + B_K0, tid, wave);
        __builtin_amdgcn_s_barrier();
        __builtin_amdgcn_s_setprio(1);
#pragma unroll
        for (int m = 0; m < 4; ++m)
#pragma unroll
            for (int n = 0; n < 4; ++n)
                acc[4 + m][n] = __builtin_amdgcn_mfma_f32_16x16x32_bf16(
                    a[m], b[n], acc[4 + m][n], 0, 0, 0);
        __builtin_amdgcn_s_setprio(0);
        // W_b: A_k1(t), B_k1(t) (oldest 4 loads) must land before P3 reads.
        if (pf) { asm volatile("s_waitcnt vmcnt(4)" ::: "memory"); }
        else    { asm volatile("s_waitcnt vmcnt(0)" ::: "memory"); }
        __builtin_amdgcn_s_barrier();

        // ===== P3: quadrant (m-half 0, ks 1); stage A_k1(t+1) =====
#pragma unroll
        for (int n = 0; n < 4; ++n) b[n] = *(const bf16x8*)(pB1 + n * 512);
#pragma unroll
        for (int m = 0; m < 4; ++m) a[m] = *(const bf16x8*)(pA1 + m * 512);
        if (pf) stage_unit(A, brow, ktn + 32, pb + A_K1, tid, wave);
        __builtin_amdgcn_s_barrier();
        __builtin_amdgcn_s_setprio(1);
#pragma unroll
        for (int m = 0; m < 4; ++m)
#pragma unroll
            for (int n = 0; n < 4; ++n)
                acc[m][n] = __builtin_amdgcn_mfma_f32_16x16x32_bf16(
                    a[m], b[n], acc[m][n], 0, 0, 0);
        __builtin_amdgcn_s_setprio(0);
        __builtin_amdgcn_s_barrier();

        // ===== P4: quadrant (m-half 1, ks 1), B reused; stage B_k1(t+1) =====
#pragma unroll
        for (int m = 0; m < 4; ++m) a[m] = *(const bf16x8*)(pA1 + 2048 + m * 512);
        if (pf) stage_unit(B, bcol, ktn + 32, pb + B_K1, tid, wave);
        __builtin_amdgcn_s_barrier();
        __builtin_amdgcn_s_setprio(1);
#pragma unroll
        for (int m = 0; m < 4; ++m)
#pragma unroll
            for (int n = 0; n < 4; ++n)
                acc[4 + m][n] = __builtin_amdgcn_mfma_f32_16x16x32_bf16(
                    a[m], b[n], acc[4 + m][n], 0, 0, 0);
        __builtin_amdgcn_s_setprio(0);
        // W_a: A_k0(t+1), B_k0(t+1) (oldest 4) must land before P1(t+1) reads.
        if (pf) {
            asm volatile("s_waitcnt vmcnt(4)" ::: "memory");
            __builtin_amdgcn_s_barrier();
        }
    }

    // ---- epilogue: C/D layout col=lane&15, row=(lane>>4)*4+j; fused bias ----
#pragma unroll
    for (int n = 0; n < 4; ++n) {
        const size_t col = bcol + wc * 64 + n * 16 + lr;
        const float bs = bias[col];
#pragma unroll
        for (int m = 0; m < 8; ++m) {
            const size_t row0 = brow + (size_t)wr * 128 + m * 16 + kg * 4;
#pragma unroll
            for (int j = 0; j < 4; ++j) {
                C[(row0 + j) * N + col] = acc[m][n][j] + bs;
            }
        }
    }
}

extern "C" void kernel_launch(void* const* d_in, const int* in_sizes, int n_in,
                              void* d_out, int out_size, void* d_ws, size_t ws_size,
                              hipStream_t stream) {
    const float* x    = (const float*)d_in[0];   // [T,B,C_IN] = [M,K]
    const float* w    = (const float*)d_in[1];   // [C_OUT,C_IN] = [N,K]
    const float* bias = (const float*)d_in[2];   // [N]
    float* out = (float*)d_out;                  // [M,N]

    unsigned short* Abf = (unsigned short*)d_ws;           // 32 MiB
    unsigned short* Bbf = Abf + (size_t)M * K;             // 32 MiB

    cvt_both<<<4096, 256, 0, stream>>>(x, w, Abf, Bbf);

    gemm_bt_bias_np<<<dim3((M / BM) * (N / BN)), 512, 0, stream>>>(Abf, Bbf, bias, out);
}

// Round 13
// 140.494 us; speedup vs baseline: 3.2524x; 1.0909x over previous
//
#include <hip/hip_runtime.h>
#include <hip/hip_bf16.h>

// SparseLinear forward as DENSE bf16 MFMA GEMM:  C = A * B^T + bias (4096^3).
// R13: leanest-sync schedule — K-complete phases, ONE counted vmcnt(4) and
// TWO barriers per K-tile (entry + end-P1), B-fragments register-held across
// the whole tile, free-running P2-P4. Stage ledger (verified):
//   p1: A_k0(t+1)->other buf   p2: A_k1(t+1)->other buf
//   p3: B_k0(t+2)->cur buf     p4: B_k1(t+2)->cur buf
// Entry vmcnt(4) retains exactly B(t+1)'s 4 loads. 256x256 tile, BK=64,
// 8 waves (2Mx4N), zero-conflict granule-XOR swizzle, setprio, fused bias.

typedef __bf16 bf16x8 __attribute__((ext_vector_type(8)));
typedef float f32x4 __attribute__((ext_vector_type(4)));

constexpr int M = 4096;   // T*B
constexpr int N = 4096;   // C_OUT
constexpr int K = 4096;   // C_IN
constexpr int BM = 256, BN = 256, BK = 64;
constexpr int NT = K / BK;          // 64 K-tiles
// One dbuf = 32768 elems (64 KiB): [A_k0][A_k1][B_k0][B_k1], each [256][32]
constexpr int DBUF = 32768;
constexpr int A_K0 = 0, A_K1 = 8192, B_K0 = 16384, B_K1 = 24576;

__device__ __forceinline__ unsigned short f2bf_rne(float f) {
    unsigned int u = __float_as_uint(f);
    u += 0x7fffu + ((u >> 16) & 1u);   // round-to-nearest-even
    return (unsigned short)(u >> 16);
}

// Fused convert: x -> Abf and w -> Bbf in one launch.
__global__ __launch_bounds__(256) void cvt_both(const float* __restrict__ x,
                                                const float* __restrict__ w,
                                                unsigned short* __restrict__ Abf,
                                                unsigned short* __restrict__ Bbf) {
    const int n8 = (M * K) / 8;
    int idx = blockIdx.x * blockDim.x + threadIdx.x;
    int stride = gridDim.x * blockDim.x;
    for (int i = idx; i < 2 * n8; i += stride) {
        const float* src;
        unsigned short* dst;
        if (i < n8) { long b = (long)i * 8;        src = x + b; dst = Abf + b; }
        else        { long b = (long)(i - n8) * 8; src = w + b; dst = Bbf + b; }
        float4 v0 = *(const float4*)(src);
        float4 v1 = *(const float4*)(src + 4);
        ushort4 r0, r1;
        r0.x = f2bf_rne(v0.x); r0.y = f2bf_rne(v0.y);
        r0.z = f2bf_rne(v0.z); r0.w = f2bf_rne(v0.w);
        r1.x = f2bf_rne(v1.x); r1.y = f2bf_rne(v1.y);
        r1.z = f2bf_rne(v1.z); r1.w = f2bf_rne(v1.w);
        *(ushort4*)(dst) = r0;
        *(ushort4*)(dst + 4) = r1;
    }
}

// Stage one k-half unit ([256 rows][32 k] = 16 KiB, 2 global_load_lds) into
// LDS (linear dest, pre-swizzled global source: cg ^= (row>>1)&3).
__device__ __forceinline__ void stage_unit(const unsigned short* __restrict__ g,
                                           size_t grow0, int kcol0,
                                           unsigned short* unitbase,
                                           int tid, int wave) {
#pragma unroll
    for (int i = 0; i < 2; ++i) {
        const int row = i * 128 + (tid >> 2);
        const int cg  = (tid & 3) ^ ((row >> 1) & 3);
        const unsigned short* src = g + (grow0 + (size_t)row) * (size_t)K
                                      + (size_t)(kcol0 + cg * 8);
        unsigned short* dst = unitbase + i * 4096 + wave * 512;
        __builtin_amdgcn_global_load_lds(
            (const __attribute__((address_space(1))) void*)src,
            (__attribute__((address_space(3))) void*)dst, 16, 0, 0);
    }
}

// One m-pair phase: 2 a-frags (both k-units) x held b[4][2], 16 MFMA.
#define PHASE(MP)                                                              \
    {                                                                          \
        bf16x8 a0k0 = *(const bf16x8*)(pA0 + (2*(MP)) * 512);                  \
        bf16x8 a1k0 = *(const bf16x8*)(pA0 + (2*(MP)+1) * 512);                \
        bf16x8 a0k1 = *(const bf16x8*)(pA1 + (2*(MP)) * 512);                  \
        bf16x8 a1k1 = *(const bf16x8*)(pA1 + (2*(MP)+1) * 512);                \
        __builtin_amdgcn_s_setprio(1);                                         \
        _Pragma("unroll")                                                      \
        for (int n = 0; n < 4; ++n) {                                          \
            acc[2*(MP)][n]   = __builtin_amdgcn_mfma_f32_16x16x32_bf16(        \
                a0k0, b[n][0], acc[2*(MP)][n], 0, 0, 0);                       \
            acc[2*(MP)+1][n] = __builtin_amdgcn_mfma_f32_16x16x32_bf16(        \
                a1k0, b[n][0], acc[2*(MP)+1][n], 0, 0, 0);                     \
        }                                                                      \
        _Pragma("unroll")                                                      \
        for (int n = 0; n < 4; ++n) {                                          \
            acc[2*(MP)][n]   = __builtin_amdgcn_mfma_f32_16x16x32_bf16(        \
                a0k1, b[n][1], acc[2*(MP)][n], 0, 0, 0);                       \
            acc[2*(MP)+1][n] = __builtin_amdgcn_mfma_f32_16x16x32_bf16(        \
                a1k1, b[n][1], acc[2*(MP)+1][n], 0, 0, 0);                     \
        }                                                                      \
        __builtin_amdgcn_s_setprio(0);                                         \
    }

__global__ __launch_bounds__(512, 2) void gemm_lean(
    const unsigned short* __restrict__ A,   // [M][K] bf16 bits
    const unsigned short* __restrict__ B,   // [N][K] bf16 bits
    const float* __restrict__ bias,         // [N]
    float* __restrict__ C)                  // [M][N] fp32
{
    __shared__ unsigned short lds[2 * DBUF];   // 128 KiB

    // XCD-aware bijective swizzle: 256 wgs, 256 % 8 == 0
    const int wg = blockIdx.x;
    const int s  = ((wg & 7) << 5) | (wg >> 3);
    const int bm = s >> 4, bn = s & 15;
    const size_t brow = (size_t)bm * BM;
    const size_t bcol = (size_t)bn * BN;

    const int tid  = threadIdx.x;
    const int wave = tid >> 6;
    const int lane = tid & 63;
    const int wr = wave >> 2;       // 0..1  (2 M-waves, 128 rows each)
    const int wc = wave & 3;        // 0..3  (4 N-waves, 64 cols each)
    const int lr = lane & 15;       // fragment row-in-16
    const int kg = lane >> 4;       // k-group 0..3

    const int a_row0 = wr * 128 + lr;
    const int b_row0 = wc * 64 + lr;
    const int aoff = a_row0 * 32 + ((kg ^ ((a_row0 >> 1) & 3)) << 3);
    const int boff = b_row0 * 32 + ((kg ^ ((b_row0 >> 1) & 3)) << 3);

    f32x4 acc[8][4];
#pragma unroll
    for (int m = 0; m < 8; ++m)
#pragma unroll
        for (int n = 0; n < 4; ++n)
            acc[m][n] = (f32x4){0.f, 0.f, 0.f, 0.f};

    // ---- prologue: B(0), A(0), B(1) = 6 units, 12 loads (oldest->newest) ----
    stage_unit(B, bcol, 0,       lds + B_K0, tid, wave);
    stage_unit(B, bcol, 32,      lds + B_K1, tid, wave);
    stage_unit(A, brow, 0,       lds + A_K0, tid, wave);
    stage_unit(A, brow, 32,      lds + A_K1, tid, wave);
    stage_unit(B, bcol, BK,      lds + DBUF + B_K0, tid, wave);
    stage_unit(B, bcol, BK + 32, lds + DBUF + B_K1, tid, wave);

    for (int t = 0; t < NT; ++t) {
        unsigned short* db = lds + (t & 1) * DBUF;        // compute buffer
        unsigned short* pb = lds + ((t & 1) ^ 1) * DBUF;  // other buffer
        const bool pf1 = (t + 1) < NT;
        const bool pf2 = (t + 2) < NT;

        // Entry wait: tile t's 4 units landed; B(t+1)'s 4 loads (newest)
        // stay in flight. Entry barrier also fences: other-buf A regions
        // (tile t-1 A, reads done before waves' P4 MFMAs -> before arrival).
        if (pf1) { asm volatile("s_waitcnt vmcnt(4)" ::: "memory"); }
        else     { asm volatile("s_waitcnt vmcnt(0)" ::: "memory"); }
        __builtin_amdgcn_s_barrier();

        const unsigned short* pA0 = db + A_K0 + aoff;
        const unsigned short* pA1 = db + A_K1 + aoff;
        const unsigned short* pB0 = db + B_K0 + boff;
        const unsigned short* pB1 = db + B_K1 + boff;

        // ===== P1: load ALL B-frags (held whole tile) + m-pair 0 =====
        bf16x8 b[4][2];
#pragma unroll
        for (int n = 0; n < 4; ++n) {
            b[n][0] = *(const bf16x8*)(pB0 + n * 512);
            b[n][1] = *(const bf16x8*)(pB1 + n * 512);
        }
        if (pf1) stage_unit(A, brow, (t + 1) * BK, pb + A_K0, tid, wave);
        PHASE(0)
        // end-P1 barrier: all waves' B-reads complete -> B regions of cur
        // buffer free for staging at P3/P4.
        __builtin_amdgcn_s_barrier();

        // ===== P2..P4: free-run (no barriers) =====
        if (pf1) stage_unit(A, brow, (t + 1) * BK + 32, pb + A_K1, tid, wave);
        PHASE(1)
        if (pf2) stage_unit(B, bcol, (t + 2) * BK, db + B_K0, tid, wave);
        PHASE(2)
        if (pf2) stage_unit(B, bcol, (t + 2) * BK + 32, db + B_K1, tid, wave);
        PHASE(3)
    }

    // ---- epilogue: C/D layout col=lane&15, row=(lane>>4)*4+j; fused bias ----
#pragma unroll
    for (int n = 0; n < 4; ++n) {
        const size_t col = bcol + wc * 64 + n * 16 + lr;
        const float bs = bias[col];
#pragma unroll
        for (int m = 0; m < 8; ++m) {
            const size_t row0 = brow + (size_t)wr * 128 + m * 16 + kg * 4;
#pragma unroll
            for (int j = 0; j < 4; ++j) {
                C[(row0 + j) * N + col] = acc[m][n][j] + bs;
            }
        }
    }
}

extern "C" void kernel_launch(void* const* d_in, const int* in_sizes, int n_in,
                              void* d_out, int out_size, void* d_ws, size_t ws_size,
                              hipStream_t stream) {
    const float* x    = (const float*)d_in[0];   // [T,B,C_IN] = [M,K]
    const float* w    = (const float*)d_in[1];   // [C_OUT,C_IN] = [N,K]
    const float* bias = (const float*)d_in[2];   // [N]
    float* out = (float*)d_out;                  // [M,N]

    unsigned short* Abf = (unsigned short*)d_ws;           // 32 MiB
    unsigned short* Bbf = Abf + (size_t)M * K;             // 32 MiB

    cvt_both<<<4096, 256, 0, stream>>>(x, w, Abf, Bbf);

    gemm_lean<<<dim3((M / BM) * (N / BN)), 512, 0, stream>>>(Abf, Bbf, bias, out);
}